// Round 1
// baseline (1113.592 us; speedup 1.0000x reference)
//
#include <hip/hip_runtime.h>

// Problem constants (from reference: M, B, D = 32, 64, 8192)
#define Mh 32
#define Bh 64
#define Dh 8192
#define KCH 256           // K-range per workgroup in gram kernel (was 1024)
#define NCH (Dh / KCH)    // 32 k-chunks -> 2048 blocks (was 512: occupancy-starved)
#define CCH 8             // d-chunks for combine

// Workspace layout (float offsets). Total ~545 KB.
#define OFF_WSY 0                       // [64][32][32]  Wsy[i][j] = s_i . y_j
#define OFF_WYY (64 * 1024)             // [64][32][32]  Wyy[i][j] = y_i . y_j
#define OFF_VS  (2 * 64 * 1024)         // [64][32]      vs[i] = s_i . frc
#define OFF_VY  (OFF_VS + 64 * 32)      // [64][32]      vy[i] = y_i . frc
#define OFF_CY  (OFF_VY + 64 * 32)      // [64][32]      g * a_i
#define OFF_CS  (OFF_CY + 64 * 32)      // [64][32]      b_i - a_i
#define OFF_G   (OFF_CS + 64 * 32)      // [64]          g per batch
#define WS_ZERO_FLOATS OFF_CY           // region that must be zeroed (atomics)

// ---------------------------------------------------------------------------
// Kernel A: batched Gram matrices. grid = 64 b x 32 k-chunks, 256 threads.
// Double-buffered LDS 32x64 tiles (XOR-4 swizzle), ONE barrier per stage.
// 4x4 register tiles on an 8x8 thread grid; 4 waves split the 64-wide K
// stage 16 each. __launch_bounds__(256,4): VGPR<=128 -> 4 blocks/CU
// (LDS 33.75KB/block -> 135KB/CU, fits 160KB).
// ---------------------------------------------------------------------------
__global__ __launch_bounds__(256, 4) void gram_kernel(
    const float* __restrict__ s, const float* __restrict__ y,
    const float* __restrict__ frc, float* __restrict__ ws)
{
    __shared__ float sT[2][2048];   // [buf][32 rows][64 k] (swizzled)
    __shared__ float yT[2][2048];
    __shared__ float fT[2][64];
    __shared__ float fR[4][64];     // per-wave vs/vy partials

    const int b  = blockIdx.x & 63;
    const int ch = blockIdx.x >> 6;
    const int k0 = ch * KCH;
    const int t  = threadIdx.x;
    const int w  = t >> 6;        // wave 0..3
    const int l  = t & 63;
    const int tx = l & 7;         // y-row group (cols of Wsy)
    const int ty = l >> 3;        // s-row group (rows of Wsy)

    float asy[4][4] = {};
    float ayy[4][4] = {};
    float avs[4] = {}, avy[4] = {};

    // staging thread -> (i, k4) mapping, two reps cover 32x16 float4s
    const int i0 = t >> 4;               // rows 0..15
    const int i1 = i0 + 16;              // rows 16..31
    const int k4 = t & 15;
    const int swz0 = (k4 << 2) ^ (((i0 >> 2) & 7) << 2);
    const int swz1 = (k4 << 2) ^ (((i1 >> 2) & 7) << 2);

    const float* sp0 = s + ((size_t)i0 * Bh + b) * Dh + k0 + (k4 << 2);
    const float* yp0 = y + ((size_t)i0 * Bh + b) * Dh + k0 + (k4 << 2);
    const float* sp1 = s + ((size_t)i1 * Bh + b) * Dh + k0 + (k4 << 2);
    const float* yp1 = y + ((size_t)i1 * Bh + b) * Dh + k0 + (k4 << 2);
    const float* fp  = frc + (size_t)b * Dh + k0 + (t << 2);

    // prefetch stage 0
    float4 sv0 = *(const float4*)sp0;
    float4 yv0 = *(const float4*)yp0;
    float4 sv1 = *(const float4*)sp1;
    float4 yv1 = *(const float4*)yp1;
    float4 fv4 = make_float4(0.f, 0.f, 0.f, 0.f);
    if (t < 16) fv4 = *(const float4*)fp;

    int p = 0;
    const int nst = KCH / 64;   // 4 stages
    for (int st = 0; st < nst; ++st) {
        // write prefetched stage into buffer p (compute of p finished >= 1
        // barrier ago: stage st-2 computed p before barrier st-1)
        *(float4*)&sT[p][i0 * 64 + swz0] = sv0;
        *(float4*)&yT[p][i0 * 64 + swz0] = yv0;
        *(float4*)&sT[p][i1 * 64 + swz1] = sv1;
        *(float4*)&yT[p][i1 * 64 + swz1] = yv1;
        if (t < 16) *(float4*)&fT[p][t << 2] = fv4;

        // issue next stage's global loads now; latency hides under compute
        if (st + 1 < nst) {
            const int o = (st + 1) * 64;
            sv0 = *(const float4*)(sp0 + o);
            yv0 = *(const float4*)(yp0 + o);
            sv1 = *(const float4*)(sp1 + o);
            yv1 = *(const float4*)(yp1 + o);
            if (t < 16) fv4 = *(const float4*)(fp + o);
        }
        __syncthreads();

        // wave w handles k in [16w, 16w+16) of this 64-wide stage
        #pragma unroll
        for (int kk = 0; kk < 16; kk += 4) {
            const int kc = (w << 4) + kk;
            float4 yxv[4];
            #pragma unroll
            for (int cc = 0; cc < 4; ++cc)
                yxv[cc] = *(const float4*)&yT[p][((tx << 2) + cc) * 64 + (kc ^ (tx << 2))];
            const float4 fv = *(const float4*)&fT[p][kc];
            #pragma unroll
            for (int aa = 0; aa < 4; ++aa) {
                const float4 sv  = *(const float4*)&sT[p][((ty << 2) + aa) * 64 + (kc ^ (ty << 2))];
                const float4 ytv = *(const float4*)&yT[p][((ty << 2) + aa) * 64 + (kc ^ (ty << 2))];
                #pragma unroll
                for (int cc = 0; cc < 4; ++cc) {
                    asy[aa][cc] += sv.x * yxv[cc].x + sv.y * yxv[cc].y
                                 + sv.z * yxv[cc].z + sv.w * yxv[cc].w;
                    ayy[aa][cc] += ytv.x * yxv[cc].x + ytv.y * yxv[cc].y
                                 + ytv.z * yxv[cc].z + ytv.w * yxv[cc].w;
                }
                avs[aa] += sv.x * fv.x + sv.y * fv.y + sv.z * fv.z + sv.w * fv.w;
                avy[aa] += ytv.x * fv.x + ytv.y * fv.y + ytv.z * fv.z + ytv.w * fv.w;
            }
        }
        p ^= 1;
    }

    // parallel cross-wave reduction: per-wave regions in the (now free)
    // staging buffers, ONE barrier, then one atomic per element.
    __syncthreads();
    float* RS = &sT[0][0];   // 4096 floats = 4 waves x 1024
    float* RY = &yT[0][0];
    #pragma unroll
    for (int aa = 0; aa < 4; ++aa) {
        #pragma unroll
        for (int cc = 0; cc < 4; ++cc) {
            const int e = ((ty << 2) + aa) * 32 + (tx << 2) + cc;
            RS[w * 1024 + e] = asy[aa][cc];
            RY[w * 1024 + e] = ayy[aa][cc];
        }
        if (tx == 0) {
            fR[w][(ty << 2) + aa]      = avs[aa];
            fR[w][32 + (ty << 2) + aa] = avy[aa];
        }
    }
    __syncthreads();

    float* WSY = ws + OFF_WSY + b * 1024;
    float* WYY = ws + OFF_WYY + b * 1024;
    for (int e = t; e < 1024; e += 256) {
        unsafeAtomicAdd(&WSY[e], RS[e] + RS[1024 + e] + RS[2048 + e] + RS[3072 + e]);
        unsafeAtomicAdd(&WYY[e], RY[e] + RY[1024 + e] + RY[2048 + e] + RY[3072 + e]);
    }
    if (t < 32) {
        unsafeAtomicAdd(&ws[OFF_VS + b * 32 + t],
                        fR[0][t] + fR[1][t] + fR[2][t] + fR[3][t]);
    } else if (t < 64) {
        const int i = t - 32;
        unsafeAtomicAdd(&ws[OFF_VY + b * 32 + i],
                        fR[0][32 + i] + fR[1][32 + i] + fR[2][32 + i] + fR[3][32 + i]);
    }
}

// ---------------------------------------------------------------------------
// Kernel B: per-b M=32 recursion on the Gram matrices, f64, one wave per b.
// Lane i owns row i (and column i) of Wsy and row i of Wyy. (unchanged)
// ---------------------------------------------------------------------------
__global__ __launch_bounds__(64) void recur_kernel(float* __restrict__ ws)
{
    const int b    = blockIdx.x;
    const int lane = threadIdx.x;
    const int i    = lane & 31;   // lanes 32..63 mirror 0..31 (writes guarded)

    const float* WSY = ws + OFF_WSY + b * 1024;
    const float* WYY = ws + OFF_WYY + b * 1024;

    float row_sy[32], col_sy[32], row_yy[32];
    #pragma unroll
    for (int j = 0; j < 32; ++j) {
        row_sy[j] = WSY[i * 32 + j];   // s_i . y_j
        col_sy[j] = WSY[j * 32 + i];   // s_j . y_i
        row_yy[j] = WYY[i * 32 + j];   // y_i . y_j
    }

    const double r = 1.0 / (double)row_sy[i];          // 1/(s_i.y_i)
    double acc = -(double)ws[OFF_VS + b * 32 + i];     // s_i.q0 running
    double a_val = 0.0;
    #pragma unroll
    for (int j = 31; j >= 0; --j) {                    // backward scan
        const double aj = __shfl(r, j) * __shfl(acc, j);
        if (i == j) a_val = aj;
        if (i < j)  acc -= aj * (double)row_sy[j];
    }

    const double g = (double)WSY[31 * 32 + 31] / (double)WYY[31 * 32 + 31];

    double u = -(double)ws[OFF_VY + b * 32 + i];       // y_i.q_f0 / g
    #pragma unroll
    for (int j = 0; j < 32; ++j)
        u -= __shfl(a_val, j) * (double)row_yy[j];
    u *= g;

    double tt = u;
    double b_val = 0.0;
    #pragma unroll
    for (int j = 0; j < 32; ++j) {                     // forward scan
        const double bj = __shfl(r, j) * __shfl(tt, j);
        if (i == j) b_val = bj;
        const double dj = __shfl(a_val, j) - bj;
        if (i > j) tt += dj * (double)col_sy[j];
    }

    if (lane < 32) {
        ws[OFF_CY + b * 32 + i] = (float)(g * a_val);
        ws[OFF_CS + b * 32 + i] = (float)(b_val - a_val);
    }
    if (lane == 0) ws[OFF_G + b] = (float)g;
}

// ---------------------------------------------------------------------------
// Kernel C: out[b,d] = g*frc[b,d] + sum_i cy[i]*y[i,b,d] + cs[i]*s[i,b,d]
// grid = 64 b x 8 d-chunks, 512 threads. The i-sum is split across two
// 256-thread halves (i<16 / i>=16) -> 4096 waves total = 16 waves/CU,
// pair-reduced through LDS. Memory-bound; goal is latency hiding.
// ---------------------------------------------------------------------------
__global__ __launch_bounds__(512) void combine_kernel(
    const float* __restrict__ s, const float* __restrict__ y,
    const float* __restrict__ frc, const float* __restrict__ ws,
    float* __restrict__ out)
{
    __shared__ float cy[32], cs[32];
    __shared__ float4 red[256];
    const int b    = blockIdx.x & 63;
    const int ch   = blockIdx.x >> 6;
    const int t    = threadIdx.x;
    const int half = t >> 8;        // 0: i in [0,16) + g*frc; 1: i in [16,32)
    const int tt   = t & 255;
    if (t < 32) { cy[t] = ws[OFF_CY + b * 32 + t]; cs[t] = ws[OFF_CS + b * 32 + t]; }
    __syncthreads();

    const int d = ch * 1024 + (tt << 2);
    float4 acc = make_float4(0.f, 0.f, 0.f, 0.f);
    if (half == 0) {
        const float g = ws[OFF_G + b];
        const float4 fv = *(const float4*)(frc + (size_t)b * Dh + d);
        acc.x = g * fv.x; acc.y = g * fv.y; acc.z = g * fv.z; acc.w = g * fv.w;
    }
    const int ib = half << 4;
    #pragma unroll 8
    for (int i = 0; i < 16; ++i) {
        const int ii = ib + i;
        const float4 yv = *(const float4*)(y + ((size_t)ii * Bh + b) * Dh + d);
        const float4 sv = *(const float4*)(s + ((size_t)ii * Bh + b) * Dh + d);
        const float a1 = cy[ii], a2 = cs[ii];
        acc.x += a1 * yv.x + a2 * sv.x;
        acc.y += a1 * yv.y + a2 * sv.y;
        acc.z += a1 * yv.z + a2 * sv.z;
        acc.w += a1 * yv.w + a2 * sv.w;
    }
    if (half) red[tt] = acc;
    __syncthreads();
    if (!half) {
        const float4 r = red[tt];
        acc.x += r.x; acc.y += r.y; acc.z += r.z; acc.w += r.w;
        *(float4*)(out + (size_t)b * Dh + d) = acc;
    }
}

extern "C" void kernel_launch(void* const* d_in, const int* in_sizes, int n_in,
                              void* d_out, int out_size, void* d_ws, size_t ws_size,
                              hipStream_t stream)
{
    const float* s   = (const float*)d_in[0];
    const float* y   = (const float*)d_in[1];
    const float* frc = (const float*)d_in[2];
    float* out = (float*)d_out;
    float* ws  = (float*)d_ws;

    // zero the atomic accumulation region (ws is poisoned before every call)
    hipMemsetAsync(d_ws, 0, (size_t)WS_ZERO_FLOATS * sizeof(float), stream);

    gram_kernel<<<dim3(Bh * NCH), dim3(256), 0, stream>>>(s, y, frc, ws);
    recur_kernel<<<dim3(Bh), dim3(64), 0, stream>>>(ws);
    combine_kernel<<<dim3(Bh * CCH), dim3(512), 0, stream>>>(s, y, frc, ws, out);
}

// Round 2
// 216.350 us; speedup vs baseline: 5.1472x; 5.1472x over previous
//
#include <hip/hip_runtime.h>

// Problem constants (from reference: M, B, D = 32, 64, 8192)
#define Mh 32
#define Bh 64
#define Dh 8192
#define KCH 256           // K-range per workgroup in gram kernel
#define NCH (Dh / KCH)    // 32 k-chunks -> 2048 blocks
#define CCH 8             // d-chunks for combine

// Workspace layout (float offsets). Total ~545 KB.
#define OFF_WSY 0                       // [64][32][32]  Wsy[i][j] = s_i . y_j
#define OFF_WYY (64 * 1024)             // [64][32][32]  Wyy[i][j] = y_i . y_j
#define OFF_VS  (2 * 64 * 1024)         // [64][32]      vs[i] = s_i . frc
#define OFF_VY  (OFF_VS + 64 * 32)      // [64][32]      vy[i] = y_i . frc
#define OFF_CY  (OFF_VY + 64 * 32)      // [64][32]      g * a_i
#define OFF_CS  (OFF_CY + 64 * 32)      // [64][32]      b_i - a_i
#define OFF_G   (OFF_CS + 64 * 32)      // [64]          g per batch
#define WS_ZERO_FLOATS OFF_CY           // region that must be zeroed (atomics)

// ---------------------------------------------------------------------------
// Kernel A: batched Gram matrices. grid = 64 b x 32 k-chunks, 256 threads.
// Double-buffered LDS 32x64 tiles (XOR-4 swizzle), ONE barrier per stage.
// 4x4 register tiles on an 8x8 thread grid; 4 waves split the 64-wide K
// stage 16 each.
// NOTE: NO min-waves __launch_bounds__ clamp. Round-1 evidence:
// __launch_bounds__(256,4) forced VGPR 164->64, spilled accumulators to
// scratch (WRITE_SIZE 4MB->2.1GB, 987us). At ~164 VGPR we get 3 blocks/CU
// (VGPR-bound; LDS 34.3KB allows 4) with zero spills.
// ---------------------------------------------------------------------------
__global__ __launch_bounds__(256) void gram_kernel(
    const float* __restrict__ s, const float* __restrict__ y,
    const float* __restrict__ frc, float* __restrict__ ws)
{
    __shared__ float sT[2][2048];   // [buf][32 rows][64 k] (swizzled)
    __shared__ float yT[2][2048];
    __shared__ float fT[2][64];
    __shared__ float fR[4][64];     // per-wave vs/vy partials

    const int b  = blockIdx.x & 63;
    const int ch = blockIdx.x >> 6;
    const int k0 = ch * KCH;
    const int t  = threadIdx.x;
    const int w  = t >> 6;        // wave 0..3
    const int l  = t & 63;
    const int tx = l & 7;         // y-row group (cols of Wsy)
    const int ty = l >> 3;        // s-row group (rows of Wsy)

    float asy[4][4] = {};
    float ayy[4][4] = {};
    float avs[4] = {}, avy[4] = {};

    // staging thread -> (i, k4) mapping, two reps cover 32x16 float4s
    const int i0 = t >> 4;               // rows 0..15
    const int i1 = i0 + 16;              // rows 16..31
    const int k4 = t & 15;
    const int swz0 = (k4 << 2) ^ (((i0 >> 2) & 7) << 2);
    const int swz1 = (k4 << 2) ^ (((i1 >> 2) & 7) << 2);

    const float* sp0 = s + ((size_t)i0 * Bh + b) * Dh + k0 + (k4 << 2);
    const float* yp0 = y + ((size_t)i0 * Bh + b) * Dh + k0 + (k4 << 2);
    const float* sp1 = s + ((size_t)i1 * Bh + b) * Dh + k0 + (k4 << 2);
    const float* yp1 = y + ((size_t)i1 * Bh + b) * Dh + k0 + (k4 << 2);
    const float* fp  = frc + (size_t)b * Dh + k0 + (t << 2);

    // prefetch stage 0
    float4 sv0 = *(const float4*)sp0;
    float4 yv0 = *(const float4*)yp0;
    float4 sv1 = *(const float4*)sp1;
    float4 yv1 = *(const float4*)yp1;
    float4 fv4 = make_float4(0.f, 0.f, 0.f, 0.f);
    if (t < 16) fv4 = *(const float4*)fp;

    int p = 0;
    const int nst = KCH / 64;   // 4 stages
    for (int st = 0; st < nst; ++st) {
        // write prefetched stage into buffer p (compute of p finished >= 1
        // barrier ago: stage st-2 computed p before barrier st-1)
        *(float4*)&sT[p][i0 * 64 + swz0] = sv0;
        *(float4*)&yT[p][i0 * 64 + swz0] = yv0;
        *(float4*)&sT[p][i1 * 64 + swz1] = sv1;
        *(float4*)&yT[p][i1 * 64 + swz1] = yv1;
        if (t < 16) *(float4*)&fT[p][t << 2] = fv4;

        // issue next stage's global loads now; latency hides under compute
        if (st + 1 < nst) {
            const int o = (st + 1) * 64;
            sv0 = *(const float4*)(sp0 + o);
            yv0 = *(const float4*)(yp0 + o);
            sv1 = *(const float4*)(sp1 + o);
            yv1 = *(const float4*)(yp1 + o);
            if (t < 16) fv4 = *(const float4*)(fp + o);
        }
        __syncthreads();

        // wave w handles k in [16w, 16w+16) of this 64-wide stage
        #pragma unroll
        for (int kk = 0; kk < 16; kk += 4) {
            const int kc = (w << 4) + kk;
            float4 yxv[4];
            #pragma unroll
            for (int cc = 0; cc < 4; ++cc)
                yxv[cc] = *(const float4*)&yT[p][((tx << 2) + cc) * 64 + (kc ^ (tx << 2))];
            const float4 fv = *(const float4*)&fT[p][kc];
            #pragma unroll
            for (int aa = 0; aa < 4; ++aa) {
                const float4 sv  = *(const float4*)&sT[p][((ty << 2) + aa) * 64 + (kc ^ (ty << 2))];
                const float4 ytv = *(const float4*)&yT[p][((ty << 2) + aa) * 64 + (kc ^ (ty << 2))];
                #pragma unroll
                for (int cc = 0; cc < 4; ++cc) {
                    asy[aa][cc] += sv.x * yxv[cc].x + sv.y * yxv[cc].y
                                 + sv.z * yxv[cc].z + sv.w * yxv[cc].w;
                    ayy[aa][cc] += ytv.x * yxv[cc].x + ytv.y * yxv[cc].y
                                 + ytv.z * yxv[cc].z + ytv.w * yxv[cc].w;
                }
                avs[aa] += sv.x * fv.x + sv.y * fv.y + sv.z * fv.z + sv.w * fv.w;
                avy[aa] += ytv.x * fv.x + ytv.y * fv.y + ytv.z * fv.z + ytv.w * fv.w;
            }
        }
        p ^= 1;
    }

    // parallel cross-wave reduction: per-wave regions in the (now free)
    // staging buffers, ONE barrier, then one atomic per element.
    __syncthreads();
    float* RS = &sT[0][0];   // 4096 floats = 4 waves x 1024
    float* RY = &yT[0][0];
    #pragma unroll
    for (int aa = 0; aa < 4; ++aa) {
        #pragma unroll
        for (int cc = 0; cc < 4; ++cc) {
            const int e = ((ty << 2) + aa) * 32 + (tx << 2) + cc;
            RS[w * 1024 + e] = asy[aa][cc];
            RY[w * 1024 + e] = ayy[aa][cc];
        }
        if (tx == 0) {
            fR[w][(ty << 2) + aa]      = avs[aa];
            fR[w][32 + (ty << 2) + aa] = avy[aa];
        }
    }
    __syncthreads();

    float* WSY = ws + OFF_WSY + b * 1024;
    float* WYY = ws + OFF_WYY + b * 1024;
    for (int e = t; e < 1024; e += 256) {
        unsafeAtomicAdd(&WSY[e], RS[e] + RS[1024 + e] + RS[2048 + e] + RS[3072 + e]);
        unsafeAtomicAdd(&WYY[e], RY[e] + RY[1024 + e] + RY[2048 + e] + RY[3072 + e]);
    }
    if (t < 32) {
        unsafeAtomicAdd(&ws[OFF_VS + b * 32 + t],
                        fR[0][t] + fR[1][t] + fR[2][t] + fR[3][t]);
    } else if (t < 64) {
        const int i = t - 32;
        unsafeAtomicAdd(&ws[OFF_VY + b * 32 + i],
                        fR[0][32 + i] + fR[1][32 + i] + fR[2][32 + i] + fR[3][32 + i]);
    }
}

// ---------------------------------------------------------------------------
// Kernel B: per-b M=32 recursion on the Gram matrices, f64, one wave per b.
// Lane i owns row i (and column i) of Wsy and row i of Wyy. (unchanged)
// ---------------------------------------------------------------------------
__global__ __launch_bounds__(64) void recur_kernel(float* __restrict__ ws)
{
    const int b    = blockIdx.x;
    const int lane = threadIdx.x;
    const int i    = lane & 31;   // lanes 32..63 mirror 0..31 (writes guarded)

    const float* WSY = ws + OFF_WSY + b * 1024;
    const float* WYY = ws + OFF_WYY + b * 1024;

    float row_sy[32], col_sy[32], row_yy[32];
    #pragma unroll
    for (int j = 0; j < 32; ++j) {
        row_sy[j] = WSY[i * 32 + j];   // s_i . y_j
        col_sy[j] = WSY[j * 32 + i];   // s_j . y_i
        row_yy[j] = WYY[i * 32 + j];   // y_i . y_j
    }

    const double r = 1.0 / (double)row_sy[i];          // 1/(s_i.y_i)
    double acc = -(double)ws[OFF_VS + b * 32 + i];     // s_i.q0 running
    double a_val = 0.0;
    #pragma unroll
    for (int j = 31; j >= 0; --j) {                    // backward scan
        const double aj = __shfl(r, j) * __shfl(acc, j);
        if (i == j) a_val = aj;
        if (i < j)  acc -= aj * (double)row_sy[j];
    }

    const double g = (double)WSY[31 * 32 + 31] / (double)WYY[31 * 32 + 31];

    double u = -(double)ws[OFF_VY + b * 32 + i];       // y_i.q_f0 / g
    #pragma unroll
    for (int j = 0; j < 32; ++j)
        u -= __shfl(a_val, j) * (double)row_yy[j];
    u *= g;

    double tt = u;
    double b_val = 0.0;
    #pragma unroll
    for (int j = 0; j < 32; ++j) {                     // forward scan
        const double bj = __shfl(r, j) * __shfl(tt, j);
        if (i == j) b_val = bj;
        const double dj = __shfl(a_val, j) - bj;
        if (i > j) tt += dj * (double)col_sy[j];
    }

    if (lane < 32) {
        ws[OFF_CY + b * 32 + i] = (float)(g * a_val);
        ws[OFF_CS + b * 32 + i] = (float)(b_val - a_val);
    }
    if (lane == 0) ws[OFF_G + b] = (float)g;
}

// ---------------------------------------------------------------------------
// Kernel C: out[b,d] = g*frc[b,d] + sum_i cy[i]*y[i,b,d] + cs[i]*s[i,b,d]
// grid = 64 b x 8 d-chunks, 512 threads. The i-sum is split across two
// 256-thread halves (i<16 / i>=16) -> 4096 waves total = 16 waves/CU,
// pair-reduced through LDS. Memory-bound; goal is latency hiding.
// ---------------------------------------------------------------------------
__global__ __launch_bounds__(512) void combine_kernel(
    const float* __restrict__ s, const float* __restrict__ y,
    const float* __restrict__ frc, const float* __restrict__ ws,
    float* __restrict__ out)
{
    __shared__ float cy[32], cs[32];
    __shared__ float4 red[256];
    const int b    = blockIdx.x & 63;
    const int ch   = blockIdx.x >> 6;
    const int t    = threadIdx.x;
    const int half = t >> 8;        // 0: i in [0,16) + g*frc; 1: i in [16,32)
    const int tt   = t & 255;
    if (t < 32) { cy[t] = ws[OFF_CY + b * 32 + t]; cs[t] = ws[OFF_CS + b * 32 + t]; }
    __syncthreads();

    const int d = ch * 1024 + (tt << 2);
    float4 acc = make_float4(0.f, 0.f, 0.f, 0.f);
    if (half == 0) {
        const float g = ws[OFF_G + b];
        const float4 fv = *(const float4*)(frc + (size_t)b * Dh + d);
        acc.x = g * fv.x; acc.y = g * fv.y; acc.z = g * fv.z; acc.w = g * fv.w;
    }
    const int ib = half << 4;
    #pragma unroll 8
    for (int i = 0; i < 16; ++i) {
        const int ii = ib + i;
        const float4 yv = *(const float4*)(y + ((size_t)ii * Bh + b) * Dh + d);
        const float4 sv = *(const float4*)(s + ((size_t)ii * Bh + b) * Dh + d);
        const float a1 = cy[ii], a2 = cs[ii];
        acc.x += a1 * yv.x + a2 * sv.x;
        acc.y += a1 * yv.y + a2 * sv.y;
        acc.z += a1 * yv.z + a2 * sv.z;
        acc.w += a1 * yv.w + a2 * sv.w;
    }
    if (half) red[tt] = acc;
    __syncthreads();
    if (!half) {
        const float4 r = red[tt];
        acc.x += r.x; acc.y += r.y; acc.z += r.z; acc.w += r.w;
        *(float4*)(out + (size_t)b * Dh + d) = acc;
    }
}

extern "C" void kernel_launch(void* const* d_in, const int* in_sizes, int n_in,
                              void* d_out, int out_size, void* d_ws, size_t ws_size,
                              hipStream_t stream)
{
    const float* s   = (const float*)d_in[0];
    const float* y   = (const float*)d_in[1];
    const float* frc = (const float*)d_in[2];
    float* out = (float*)d_out;
    float* ws  = (float*)d_ws;

    // zero the atomic accumulation region (ws is poisoned before every call)
    hipMemsetAsync(d_ws, 0, (size_t)WS_ZERO_FLOATS * sizeof(float), stream);

    gram_kernel<<<dim3(Bh * NCH), dim3(256), 0, stream>>>(s, y, frc, ws);
    recur_kernel<<<dim3(Bh), dim3(64), 0, stream>>>(ws);
    combine_kernel<<<dim3(Bh * CCH), dim3(512), 0, stream>>>(s, y, frc, ws, out);
}

// Round 3
// 178.671 us; speedup vs baseline: 6.2326x; 1.2109x over previous
//
#include <hip/hip_runtime.h>

// Problem constants (from reference: M, B, D = 32, 64, 8192)
#define Mh 32
#define Bh 64
#define Dh 8192
#define KCH 256           // K-range per workgroup in gram kernel
#define NCH (Dh / KCH)    // 32 k-chunks -> 2048 blocks
#define CCH 8             // d-chunks for combine

// Workspace layout (float offsets). Total ~545 KB.
#define OFF_WSY 0                       // [64][32][32]  Wsy[i][j] = s_i . y_j
#define OFF_WYY (64 * 1024)             // [64][32][32]  Wyy[i][j] = y_i . y_j
#define OFF_VS  (2 * 64 * 1024)         // [64][32]      vs[i] = s_i . frc
#define OFF_VY  (OFF_VS + 64 * 32)      // [64][32]      vy[i] = y_i . frc
#define OFF_CY  (OFF_VY + 64 * 32)      // [64][32]      g * a_i
#define OFF_CS  (OFF_CY + 64 * 32)      // [64][32]      b_i - a_i
#define OFF_G   (OFF_CS + 64 * 32)      // [64]          g per batch
#define WS_ZERO_FLOATS OFF_CY           // region that must be zeroed (atomics)

typedef __attribute__((ext_vector_type(4)))  __bf16 bf16x4;
typedef __attribute__((ext_vector_type(8)))  __bf16 bf16x8;
typedef __attribute__((ext_vector_type(16))) float  f32x16;

// fp32 -> bf16 hi/lo split: x ~= hi + lo with |err| ~ 2^-18 |x|
__device__ __forceinline__ void split4(const float4 v, bf16x4& h, bf16x4& l)
{
    h[0] = (__bf16)v.x; h[1] = (__bf16)v.y; h[2] = (__bf16)v.z; h[3] = (__bf16)v.w;
    l[0] = (__bf16)(v.x - (float)h[0]);
    l[1] = (__bf16)(v.y - (float)h[1]);
    l[2] = (__bf16)(v.z - (float)h[2]);
    l[3] = (__bf16)(v.w - (float)h[3]);
}

// ---------------------------------------------------------------------------
// Kernel A: batched Gram matrices via bf16-split MFMA.
// grid = 64 b x 32 k-chunks, 256 threads (4 waves).
// Round-2 evidence: fp32-VALU version was LDS-BW-bound (52 ds_read_b128 per
// wave-stage, 42% VALUBusy, 14.6% of FMA peak, 93 us). MFMA path: per
// wave-stage only 4 ds_read_b128 + 6 MFMAs; matrix-pipe total ~3 us.
// Gram entries via hi*hi + hi*lo + lo*hi (rel err ~4e-6, comparable to fp32
// accumulation); f64 recursion unchanged. vs/vy stay fp32 in registers.
// A-frag of 32x32x16: lane holds row (l&31), k = 8*(l>>5)+e  -> identical
// layout for B-frag of Y^T, so yH/yL fragments serve A(Wyy) and B(both).
// C/D: col = l&31, row = (r&3) + 8*(r>>2) + 4*(l>>5)   [m74/m101 verified]
// NO min-waves launch_bounds clamp (round-1: clamp -> spill -> 987 us).
// ---------------------------------------------------------------------------
__global__ __launch_bounds__(256) void gram_kernel(
    const float* __restrict__ s, const float* __restrict__ y,
    const float* __restrict__ frc, float* __restrict__ ws)
{
    // [buf][mat: sH,sL,yH,yL][32 rows * 64 k] bf16, XOR-8 swizzled = 32 KB
    __shared__ __align__(16) __bf16 lds[2][4][2048];

    const int b  = blockIdx.x & 63;
    const int ch = blockIdx.x >> 6;
    const int k0 = ch * KCH;
    const int t  = threadIdx.x;
    const int w  = t >> 6;        // wave 0..3 -> k-slice w of each 64-k stage
    const int l  = t & 63;

    f32x16 accSY = {};            // partial Wsy (this wave's k subset)
    f32x16 accYY = {};            // partial Wyy
    float avs0 = 0.f, avs1 = 0.f, avy0 = 0.f, avy1 = 0.f;

    // staging: thread t covers rows i0 (0..15) and i1 (16..31), 4 k's each
    const int i0 = t >> 4, i1 = i0 + 16, k4 = t & 15;
    const int e0 = i0 * 64 + ((k4 << 2) ^ ((i0 & 7) << 3));
    const int e1 = i1 * 64 + ((k4 << 2) ^ ((i1 & 7) << 3));

    const float* sp0 = s + ((size_t)i0 * Bh + b) * Dh + k0 + (k4 << 2);
    const float* yp0 = y + ((size_t)i0 * Bh + b) * Dh + k0 + (k4 << 2);
    const float* sp1 = s + ((size_t)i1 * Bh + b) * Dh + k0 + (k4 << 2);
    const float* yp1 = y + ((size_t)i1 * Bh + b) * Dh + k0 + (k4 << 2);
    const float* fp  = frc + (size_t)b * Dh + k0 + (k4 << 2);

    // prefetch stage 0
    float4 sv0 = *(const float4*)sp0;
    float4 yv0 = *(const float4*)yp0;
    float4 sv1 = *(const float4*)sp1;
    float4 yv1 = *(const float4*)yp1;
    float4 fv  = *(const float4*)fp;

    // MFMA fragment address: lane l reads row (l&31), 8 bf16 at k-offset
    // w*16 + 8*(l>>5), with the same XOR swizzle (16B-granule aligned).
    const int row = l & 31;
    const int fo  = (w << 4) + ((l >> 5) << 3);
    const int fe  = row * 64 + (fo ^ ((row & 7) << 3));

    int p = 0;
    const int nst = KCH / 64;   // 4 stages
    for (int st = 0; st < nst; ++st) {
        // convert + write prefetched stage into buffer p
        bf16x4 h, lo;
        split4(sv0, h, lo); *(bf16x4*)&lds[p][0][e0] = h; *(bf16x4*)&lds[p][1][e0] = lo;
        split4(yv0, h, lo); *(bf16x4*)&lds[p][2][e0] = h; *(bf16x4*)&lds[p][3][e0] = lo;
        split4(sv1, h, lo); *(bf16x4*)&lds[p][0][e1] = h; *(bf16x4*)&lds[p][1][e1] = lo;
        split4(yv1, h, lo); *(bf16x4*)&lds[p][2][e1] = h; *(bf16x4*)&lds[p][3][e1] = lo;

        // frc dot-product partials on the exact fp32 values (no bf16 loss)
        avs0 += sv0.x * fv.x + sv0.y * fv.y + sv0.z * fv.z + sv0.w * fv.w;
        avy0 += yv0.x * fv.x + yv0.y * fv.y + yv0.z * fv.z + yv0.w * fv.w;
        avs1 += sv1.x * fv.x + sv1.y * fv.y + sv1.z * fv.z + sv1.w * fv.w;
        avy1 += yv1.x * fv.x + yv1.y * fv.y + yv1.z * fv.z + yv1.w * fv.w;

        // issue next stage's global loads; latency hides under MFMA phase
        if (st + 1 < nst) {
            const int o = (st + 1) * 64;
            sv0 = *(const float4*)(sp0 + o);
            yv0 = *(const float4*)(yp0 + o);
            sv1 = *(const float4*)(sp1 + o);
            yv1 = *(const float4*)(yp1 + o);
            fv  = *(const float4*)(fp + o);
        }
        __syncthreads();

        // wave w: its 16-k slice of this stage, 4 frag reads + 6 MFMAs
        const bf16x8 aSH = *(const bf16x8*)&lds[p][0][fe];
        const bf16x8 aSL = *(const bf16x8*)&lds[p][1][fe];
        const bf16x8 aYH = *(const bf16x8*)&lds[p][2][fe];
        const bf16x8 aYL = *(const bf16x8*)&lds[p][3][fe];
        accSY = __builtin_amdgcn_mfma_f32_32x32x16_bf16(aSH, aYH, accSY, 0, 0, 0);
        accYY = __builtin_amdgcn_mfma_f32_32x32x16_bf16(aYH, aYH, accYY, 0, 0, 0);
        accSY = __builtin_amdgcn_mfma_f32_32x32x16_bf16(aSH, aYL, accSY, 0, 0, 0);
        accYY = __builtin_amdgcn_mfma_f32_32x32x16_bf16(aYH, aYL, accYY, 0, 0, 0);
        accSY = __builtin_amdgcn_mfma_f32_32x32x16_bf16(aSL, aYH, accSY, 0, 0, 0);
        accYY = __builtin_amdgcn_mfma_f32_32x32x16_bf16(aYL, aYH, accYY, 0, 0, 0);
        p ^= 1;
    }

    // vs/vy: butterfly over the 16 threads sharing each row, then atomics
    #pragma unroll
    for (int m = 1; m < 16; m <<= 1) {
        avs0 += __shfl_xor(avs0, m);
        avs1 += __shfl_xor(avs1, m);
        avy0 += __shfl_xor(avy0, m);
        avy1 += __shfl_xor(avy1, m);
    }
    const int g16 = t & 15;
    if      (g16 == 0) unsafeAtomicAdd(&ws[OFF_VS + b * 32 + i0], avs0);
    else if (g16 == 1) unsafeAtomicAdd(&ws[OFF_VS + b * 32 + i1], avs1);
    else if (g16 == 2) unsafeAtomicAdd(&ws[OFF_VY + b * 32 + i0], avy0);
    else if (g16 == 3) unsafeAtomicAdd(&ws[OFF_VY + b * 32 + i1], avy1);

    // cross-wave reduction of the 32x32 partials through the freed LDS
    __syncthreads();
    float* RS = (float*)&lds[0][0][0];   // 4 waves x 1024 floats (Wsy)
    float* RY = RS + 4096;               // 4 waves x 1024 floats (Wyy)
    #pragma unroll
    for (int r = 0; r < 16; ++r) {
        const int i = (r & 3) + ((r >> 2) << 3) + ((l >> 5) << 2);
        const int j = l & 31;
        RS[w * 1024 + i * 32 + j] = accSY[r];
        RY[w * 1024 + i * 32 + j] = accYY[r];
    }
    __syncthreads();

    float* WSY = ws + OFF_WSY + b * 1024;
    float* WYY = ws + OFF_WYY + b * 1024;
    for (int e = t; e < 1024; e += 256) {
        unsafeAtomicAdd(&WSY[e], RS[e] + RS[1024 + e] + RS[2048 + e] + RS[3072 + e]);
        unsafeAtomicAdd(&WYY[e], RY[e] + RY[1024 + e] + RY[2048 + e] + RY[3072 + e]);
    }
}

// ---------------------------------------------------------------------------
// Kernel B: per-b M=32 recursion on the Gram matrices, f64, one wave per b.
// Lane i owns row i (and column i) of Wsy and row i of Wyy. (unchanged)
// ---------------------------------------------------------------------------
__global__ __launch_bounds__(64) void recur_kernel(float* __restrict__ ws)
{
    const int b    = blockIdx.x;
    const int lane = threadIdx.x;
    const int i    = lane & 31;   // lanes 32..63 mirror 0..31 (writes guarded)

    const float* WSY = ws + OFF_WSY + b * 1024;
    const float* WYY = ws + OFF_WYY + b * 1024;

    float row_sy[32], col_sy[32], row_yy[32];
    #pragma unroll
    for (int j = 0; j < 32; ++j) {
        row_sy[j] = WSY[i * 32 + j];   // s_i . y_j
        col_sy[j] = WSY[j * 32 + i];   // s_j . y_i
        row_yy[j] = WYY[i * 32 + j];   // y_i . y_j
    }

    const double r = 1.0 / (double)row_sy[i];          // 1/(s_i.y_i)
    double acc = -(double)ws[OFF_VS + b * 32 + i];     // s_i.q0 running
    double a_val = 0.0;
    #pragma unroll
    for (int j = 31; j >= 0; --j) {                    // backward scan
        const double aj = __shfl(r, j) * __shfl(acc, j);
        if (i == j) a_val = aj;
        if (i < j)  acc -= aj * (double)row_sy[j];
    }

    const double g = (double)WSY[31 * 32 + 31] / (double)WYY[31 * 32 + 31];

    double u = -(double)ws[OFF_VY + b * 32 + i];       // y_i.q_f0 / g
    #pragma unroll
    for (int j = 0; j < 32; ++j)
        u -= __shfl(a_val, j) * (double)row_yy[j];
    u *= g;

    double tt = u;
    double b_val = 0.0;
    #pragma unroll
    for (int j = 0; j < 32; ++j) {                     // forward scan
        const double bj = __shfl(r, j) * __shfl(tt, j);
        if (i == j) b_val = bj;
        const double dj = __shfl(a_val, j) - bj;
        if (i > j) tt += dj * (double)col_sy[j];
    }

    if (lane < 32) {
        ws[OFF_CY + b * 32 + i] = (float)(g * a_val);
        ws[OFF_CS + b * 32 + i] = (float)(b_val - a_val);
    }
    if (lane == 0) ws[OFF_G + b] = (float)g;
}

// ---------------------------------------------------------------------------
// Kernel C: out[b,d] = g*frc[b,d] + sum_i cy[i]*y[i,b,d] + cs[i]*s[i,b,d]
// grid = 64 b x 8 d-chunks, 1024 threads (16 waves). i-sum split 4-way
// across thread quarters (8 i's + frc for q==0), LDS tree reduce at end.
// 2 blocks/CU x 16 waves = 32 waves/CU = 100% occupancy for streaming.
// ---------------------------------------------------------------------------
__global__ __launch_bounds__(1024) void combine_kernel(
    const float* __restrict__ s, const float* __restrict__ y,
    const float* __restrict__ frc, const float* __restrict__ ws,
    float* __restrict__ out)
{
    __shared__ float cy[32], cs[32];
    __shared__ float4 red[3][256];
    const int b  = blockIdx.x & 63;
    const int ch = blockIdx.x >> 6;
    const int t  = threadIdx.x;
    const int q  = t >> 8;          // quarter 0..3: i in [8q, 8q+8)
    const int tt = t & 255;
    if (t < 32) { cy[t] = ws[OFF_CY + b * 32 + t]; cs[t] = ws[OFF_CS + b * 32 + t]; }
    __syncthreads();

    const int d = ch * 1024 + (tt << 2);
    float4 acc = make_float4(0.f, 0.f, 0.f, 0.f);
    if (q == 0) {
        const float g = ws[OFF_G + b];
        const float4 fv = *(const float4*)(frc + (size_t)b * Dh + d);
        acc.x = g * fv.x; acc.y = g * fv.y; acc.z = g * fv.z; acc.w = g * fv.w;
    }
    const int ib = q << 3;
    #pragma unroll
    for (int i2 = 0; i2 < 8; ++i2) {
        const int i = ib + i2;
        const float4 yv = *(const float4*)(y + ((size_t)i * Bh + b) * Dh + d);
        const float4 sv = *(const float4*)(s + ((size_t)i * Bh + b) * Dh + d);
        const float a1 = cy[i], a2 = cs[i];
        acc.x += a1 * yv.x + a2 * sv.x;
        acc.y += a1 * yv.y + a2 * sv.y;
        acc.z += a1 * yv.z + a2 * sv.z;
        acc.w += a1 * yv.w + a2 * sv.w;
    }
    if (q) red[q - 1][tt] = acc;
    __syncthreads();
    if (q == 0) {
        const float4 r0 = red[0][tt], r1 = red[1][tt], r2 = red[2][tt];
        acc.x += r0.x + r1.x + r2.x;
        acc.y += r0.y + r1.y + r2.y;
        acc.z += r0.z + r1.z + r2.z;
        acc.w += r0.w + r1.w + r2.w;
        *(float4*)(out + (size_t)b * Dh + d) = acc;
    }
}

extern "C" void kernel_launch(void* const* d_in, const int* in_sizes, int n_in,
                              void* d_out, int out_size, void* d_ws, size_t ws_size,
                              hipStream_t stream)
{
    const float* s   = (const float*)d_in[0];
    const float* y   = (const float*)d_in[1];
    const float* frc = (const float*)d_in[2];
    float* out = (float*)d_out;
    float* ws  = (float*)d_ws;

    // zero the atomic accumulation region (ws is poisoned before every call)
    hipMemsetAsync(d_ws, 0, (size_t)WS_ZERO_FLOATS * sizeof(float), stream);

    gram_kernel<<<dim3(Bh * NCH), dim3(256), 0, stream>>>(s, y, frc, ws);
    recur_kernel<<<dim3(Bh), dim3(64), 0, stream>>>(ws);
    combine_kernel<<<dim3(Bh * CCH), dim3(1024), 0, stream>>>(s, y, frc, ws, out);
}